// Round 10
// baseline (117.284 us; speedup 1.0000x reference)
//
#include <hip/hip_runtime.h>
#include <hip/hip_bf16.h>
#include <math.h>

#define BATCH 32
#define CDIM  128
#define NTOT  4096
#define NCH   32           // k1 chunks per batch (grid 1024 -> 3 blocks/CU)
#define CHN   128          // n per k1 block
#define TN    64           // n per subtile
#define NCH3  16           // k3 chunks per batch

typedef __attribute__((ext_vector_type(4))) float f32x4;
typedef __attribute__((ext_vector_type(8))) short s16x8;

// ---- ws layout (float offsets) ----
#define PC_OFF  0
#define PC_SIZE (BATCH * 4 * NCH * 32 * 32)   // 4,194,304 f
#define PS_OFF  (PC_OFF + PC_SIZE)
#define PS_SIZE (BATCH * 4 * NCH * 32)        // 131,072 f
#define MBF_OFF (PS_OFF + PS_SIZE)
#define MBF_SIZE (BATCH * CDIM * CDIM / 2)    // 262,144 f
#define CTX_OFF (MBF_OFF + MBF_SIZE)
#define CTX_SIZE (BATCH * 4 * 1024)           // 131,072 f
#define XBT_OFF (CTX_OFF + CTX_SIZE)
#define XBT_SIZE (BATCH * CDIM * NTOT / 2)    // 8,388,608 f
#define NEED_BYTES ((size_t)(XBT_OFF + XBT_SIZE) * 4)   // ~52.4 MB

static __device__ __forceinline__ unsigned short f2bf(float f) {
    return __builtin_bit_cast(unsigned short, __float2bfloat16(f));
}
static __device__ __forceinline__ unsigned int pack2(float a, float b) {
    return (unsigned int)f2bf(a) | ((unsigned int)f2bf(b) << 16);
}
static __device__ __forceinline__ s16x8 ld_frag_lds(const unsigned int* p, int d0) {
    int4 t;
    t.x = (int)p[d0]; t.y = (int)p[d0 + 1];
    t.z = (int)p[d0 + 2]; t.w = (int)p[d0 + 3];
    return __builtin_bit_cast(s16x8, t);
}

// staging: fp32 tile -> LDS bf16 [n][c], 65 dw rows (R5/R6-verified)
static __device__ __forceinline__ void stage_xT(const float* __restrict__ xc,
                                                unsigned int* __restrict__ xsd,
                                                int tid) {
    const int m  = tid & 15;
    const int cg = tid >> 4;
#pragma unroll
    for (int p = 0; p < 4; ++p) {
        const int c = 2 * cg + 32 * p;
        const f32x4 a0 = *reinterpret_cast<const f32x4*>(xc + (size_t)c * NTOT + 4 * m);
        const f32x4 a1 = *reinterpret_cast<const f32x4*>(xc + (size_t)(c + 1) * NTOT + 4 * m);
#pragma unroll
        for (int jj = 0; jj < 4; ++jj)
            xsd[(4 * m + jj) * 65 + (c >> 1)] = pack2(a0[jj], a1[jj]);
    }
}

// ---------------------------------------------------------------------------
// k1: KV = W_kv @ x_chunk (MFMA), exp, partial s/C2.
// NCH=32: grid 1024 -> 3 blocks/CU (LDS 51.5 KB); direct LDS staging
// (no reg pipeline -> VGPR ~116-120, 4 waves/SIMD budget); 2 barriers/subtile.
// TLP (12 waves/CU) hides stage latency instead of ILP.
// ---------------------------------------------------------------------------
template <bool XBT>
__global__ __launch_bounds__(256)
void k1_ctx(const float* __restrict__ x, const float* __restrict__ wqkv,
            float* __restrict__ ws) {
    __shared__ __attribute__((aligned(16))) unsigned short xsT[64 * 130];    // 16,640 B
    __shared__ __attribute__((aligned(16))) unsigned short ekv[8 * 32 * 68]; // 34,816 B

    const int j = blockIdx.x, b = blockIdx.y;
    const int tid = threadIdx.x;
    const int l = tid & 63;
    const int w = tid >> 6;
    const int m = l & 15, hq = l >> 4;

    // persistent A fragments: W_kv rows 128 + 64w + 16tm + m, k = 32kt + 8hq
    s16x8 afr[4][4];
#pragma unroll
    for (int tm = 0; tm < 4; ++tm)
#pragma unroll
        for (int kt = 0; kt < 4; ++kt) {
            const float* wr = wqkv +
                (size_t)(CDIM + 64 * w + 16 * tm + m) * CDIM + 32 * kt + 8 * hq;
            const f32x4 u0 = *reinterpret_cast<const f32x4*>(wr);
            const f32x4 u1 = *reinterpret_cast<const f32x4*>(wr + 4);
            int4 t4;
            t4.x = (int)pack2(u0[0], u0[1]); t4.y = (int)pack2(u0[2], u0[3]);
            t4.z = (int)pack2(u1[0], u1[1]); t4.w = (int)pack2(u1[2], u1[3]);
            afr[tm][kt] = __builtin_bit_cast(s16x8, t4);
        }

    f32x4 cacc[2][2] = {};
    float sacc[4][4] = {};
    const float* xc = x + (size_t)b * CDIM * NTOT + j * CHN;
    unsigned int* xsd = (unsigned int*)xsT;
    unsigned int* ekvd = (unsigned int*)ekv;

    for (int it = 0; it < CHN / TN; ++it) {
        stage_xT(xc + it * TN, xsd, tid);   // global -> LDS (TLP hides latency)
        __syncthreads();                    // S1: xsT ready

        // KV GEMM
        f32x4 acc[4][4] = {};
#pragma unroll
        for (int kt = 0; kt < 4; ++kt) {
#pragma unroll
            for (int tn = 0; tn < 4; ++tn) {
                const s16x8 bfr = ld_frag_lds(xsd, (16 * tn + m) * 65 + 16 * kt + 4 * hq);
#pragma unroll
                for (int tm = 0; tm < 4; ++tm)
                    acc[tm][tn] = __builtin_amdgcn_mfma_f32_16x16x32_bf16(
                        afr[tm][kt], bfr, acc[tm][tn], 0, 0, 0);
            }
        }

        // persist swizzled bf16 tile for k3 (tile = b*64 + j*2 + it)
        if constexpr (XBT) {
            unsigned int* tb = (unsigned int*)(ws + XBT_OFF) +
                               ((size_t)b * 64 + j * 2 + it) * 4096;
            const int n = tid >> 2, qt = tid & 3;
#pragma unroll
            for (int p = 0; p < 4; ++p) {
                const int cdl = 16 * p + 4 * qt;
                const int src = n * 65 + (cdl ^ ((n & 7) << 2));
                uint4 v;
                v.x = xsd[src]; v.y = xsd[src + 1];
                v.z = xsd[src + 2]; v.w = xsd[src + 3];
                *reinterpret_cast<uint4*>(tb + (size_t)n * 64 + cdl) = v;
            }
        }

        // exp(K) -> ekv groups 0..3, V -> groups 4..7 (row stride 68 bf16)
        if (w < 2) {
#pragma unroll
            for (int tm = 0; tm < 4; ++tm)
#pragma unroll
                for (int tn = 0; tn < 4; ++tn)
#pragma unroll
                    for (int r = 0; r < 4; ++r) {
                        const int dg = 64 * w + 16 * tm + 4 * hq + r;
                        const float e = __expf(acc[tm][tn][r]);
                        sacc[tm][r] += e;
                        ekv[((dg >> 5) * 32 + (dg & 31)) * 68 + 16 * tn + m] = f2bf(e);
                    }
        } else {
#pragma unroll
            for (int tm = 0; tm < 4; ++tm)
#pragma unroll
                for (int tn = 0; tn < 4; ++tn)
#pragma unroll
                    for (int r = 0; r < 4; ++r) {
                        const int eg = 64 * (w - 2) + 16 * tm + 4 * hq + r;
                        ekv[((4 + (eg >> 5)) * 32 + (eg & 31)) * 68 + 16 * tn + m] =
                            f2bf(acc[tm][tn][r]);
                    }
        }
        __syncthreads();                 // S2: ekv ready, xsT reads done

        // context MFMA: head = w; rows stride 34 dwords
#pragma unroll
        for (int kt = 0; kt < 2; ++kt) {
            s16x8 va[2], eb[2];
#pragma unroll
            for (int t = 0; t < 2; ++t) {
                va[t] = ld_frag_lds(ekvd,
                    ((4 + w) * 32 + 16 * t + m) * 34 + 16 * kt + 4 * hq);
                eb[t] = ld_frag_lds(ekvd,
                    (w * 32 + 16 * t + m) * 34 + 16 * kt + 4 * hq);
            }
#pragma unroll
            for (int tm = 0; tm < 2; ++tm)
#pragma unroll
                for (int tn = 0; tn < 2; ++tn)
                    cacc[tm][tn] = __builtin_amdgcn_mfma_f32_16x16x32_bf16(
                        va[tm], eb[tn], cacc[tm][tn], 0, 0, 0);
        }
        // next iter's stage_xT is WAR-safe: all xsT readers passed S2
    }

    float* pc = ws + PC_OFF + (size_t)((b * 4 + w) * NCH + j) * 1024;
#pragma unroll
    for (int tm = 0; tm < 2; ++tm)
#pragma unroll
        for (int tn = 0; tn < 2; ++tn)
#pragma unroll
            for (int r = 0; r < 4; ++r)
                pc[(16 * tm + 4 * hq + r) * 32 + 16 * tn + m] = cacc[tm][tn][r];

    if (w < 2) {
#pragma unroll
        for (int tm = 0; tm < 4; ++tm)
#pragma unroll
            for (int r = 0; r < 4; ++r) {
                float s = sacc[tm][r];
                s += __shfl_xor(s, 1);
                s += __shfl_xor(s, 2);
                s += __shfl_xor(s, 4);
                s += __shfl_xor(s, 8);
                if (m == 0) {
                    const int dg = 64 * w + 16 * tm + 4 * hq + r;
                    ws[PS_OFF + (size_t)((b * 4 + (dg >> 5)) * NCH + j) * 32 + (dg & 31)] = s;
                }
            }
    }
}

// ---------------------------------------------------------------------------
// k2a: merge partials -> normalized ctx. One block per (b,h).
// ---------------------------------------------------------------------------
__global__ __launch_bounds__(256)
void k2a_ctx(float* __restrict__ ws) {
    const int bh = blockIdx.x;
    const int tid = threadIdx.x;
    __shared__ float stotS[32];
    if (tid < 32) {
        float s = 0.f;
        for (int jj = 0; jj < NCH; ++jj)
            s += ws[PS_OFF + (size_t)(bh * NCH + jj) * 32 + tid];
        stotS[tid] = s;
    }
    __syncthreads();
#pragma unroll
    for (int k = 0; k < 4; ++k) {
        const int idx = tid + 256 * k;  // e*32 + d
        float c = 0.f;
        for (int jj = 0; jj < NCH; ++jj)
            c += ws[PC_OFF + (size_t)(bh * NCH + jj) * 1024 + idx];
        ws[CTX_OFF + (size_t)bh * 1024 + idx] = c / stotS[idx & 31];
    }
}

// ---------------------------------------------------------------------------
// k2b: M[b] = W_out . BD(ctx) . W_q -> bf16.  grid (4 o-tiles, 32 batches).
// ---------------------------------------------------------------------------
__global__ __launch_bounds__(256)
void k2b_buildM(const float* __restrict__ wqkv, const float* __restrict__ wout,
                float* __restrict__ ws) {
    const int oq = blockIdx.x;
    const int b  = blockIdx.y;
    const int tid = threadIdx.x;

    __shared__ __attribute__((aligned(16))) float smA[8704];
    __shared__ float G[32][133];
    float* ctxs  = smA;          // [hd][33]
    float* wouts = smA + 4224;   // [o][133]
    unsigned int* wqs = (unsigned int*)smA;  // phase B: [hd][68] dwords

#pragma unroll
    for (int k = 0; k < 16; ++k) {
        const int fid = tid + 256 * k;          // h*1024 + e*32 + d
        const int h = fid >> 10, rem = fid & 1023;
        const int e = rem >> 5, d = rem & 31;
        ctxs[(h * 32 + d) * 33 + e] = ws[CTX_OFF + (size_t)b * 4096 + fid];
    }
#pragma unroll
    for (int k = 0; k < 16; ++k) {
        const int fid = tid + 256 * k;          // o*128 + c
        const int o = fid >> 7, c = fid & 127;
        wouts[o * 133 + c] = wout[(size_t)(oq * 32 + o) * CDIM + c];
    }
    __syncthreads();

    {
        const int o2 = tid & 31;
        const int g8 = tid >> 5;
#pragma unroll
        for (int i = 0; i < 16; ++i) {
            const int hd = g8 * 16 + i;
            const int h = hd >> 5;
            float acc = 0.f;
#pragma unroll
            for (int e = 0; e < 32; ++e)
                acc = fmaf(wouts[o2 * 133 + h * 32 + e], ctxs[hd * 33 + e], acc);
            G[o2][hd] = acc;
        }
    }
    __syncthreads();

    {
#pragma unroll
        for (int k = 0; k < 32; ++k) {
            const int fid = tid + 256 * k;      // hd*64 + cd
            const int hd = fid >> 6, cd = fid & 63;
            const float2 wv =
                *reinterpret_cast<const float2*>(wqkv + (size_t)hd * CDIM + 2 * cd);
            wqs[hd * 68 + cd] = pack2(wv.x, wv.y);
        }
    }
    __syncthreads();

    {
        const int o3 = tid >> 3;
        const int c0 = tid & 7;
        float Macc[16];
#pragma unroll
        for (int i = 0; i < 16; ++i) Macc[i] = 0.f;
        for (int hd = 0; hd < 128; ++hd) {
            const float gv = G[o3][hd];
            const uint4 w0 = *reinterpret_cast<const uint4*>(&wqs[hd * 68 + c0 * 8]);
            const uint4 w1 = *reinterpret_cast<const uint4*>(&wqs[hd * 68 + c0 * 8 + 4]);
            const unsigned int dw[8] = {w0.x, w0.y, w0.z, w0.w, w1.x, w1.y, w1.z, w1.w};
#pragma unroll
            for (int q = 0; q < 8; ++q) {
                const float lo = __builtin_bit_cast(float, dw[q] << 16);
                const float hi = __builtin_bit_cast(float, dw[q] & 0xffff0000u);
                Macc[2 * q]     = fmaf(gv, lo, Macc[2 * q]);
                Macc[2 * q + 1] = fmaf(gv, hi, Macc[2 * q + 1]);
            }
        }
        unsigned int* mpd = (unsigned int*)((unsigned short*)(ws + MBF_OFF) +
                                            (size_t)b * CDIM * CDIM) +
                            (oq * 32 + o3) * 64 + c0 * 8;
        uint4 s0, s1;
        s0.x = pack2(Macc[0], Macc[1]);   s0.y = pack2(Macc[2], Macc[3]);
        s0.z = pack2(Macc[4], Macc[5]);   s0.w = pack2(Macc[6], Macc[7]);
        s1.x = pack2(Macc[8], Macc[9]);   s1.y = pack2(Macc[10], Macc[11]);
        s1.z = pack2(Macc[12], Macc[13]); s1.w = pack2(Macc[14], Macc[15]);
        *reinterpret_cast<uint4*>(mpd) = s0;
        *reinterpret_cast<uint4*>(mpd + 4) = s1;
    }
}

// ---------------------------------------------------------------------------
// k3: out[b] = M_bf16[b] @ x_bf16[b] + b_out.  (R6/R9-verified: plain uint4
// reg-copy of pre-swizzled tiles, 2 syncthreads/iter.)
// ---------------------------------------------------------------------------
template <bool XBT>
__global__ __launch_bounds__(256)
void k3_final(const float* __restrict__ x, const float* __restrict__ bout,
              const float* __restrict__ ws, float* __restrict__ out) {
    __shared__ __attribute__((aligned(16))) unsigned int xsd[4160];

    const int j = blockIdx.x, b = blockIdx.y;
    const int tid = threadIdx.x, l = tid & 63, w = tid >> 6;
    const int m = l & 15, hq = l >> 4;

    const unsigned short* mbf =
        (const unsigned short*)(ws + MBF_OFF) + (size_t)b * CDIM * CDIM;
    s16x8 afr[2][4];
#pragma unroll
    for (int tm = 0; tm < 2; ++tm)
#pragma unroll
        for (int kt = 0; kt < 4; ++kt)
            afr[tm][kt] = *reinterpret_cast<const s16x8*>(
                mbf + (size_t)(32 * w + 16 * tm + m) * CDIM + 32 * kt + 8 * hq);
    float bias[2][4];
#pragma unroll
    for (int tm = 0; tm < 2; ++tm)
#pragma unroll
        for (int r = 0; r < 4; ++r)
            bias[tm][r] = bout[32 * w + 16 * tm + 4 * hq + r];

    const float* xc = x + (size_t)b * CDIM * NTOT + j * 256;
    float* oc = out + (size_t)b * CDIM * NTOT + j * 256;
    const unsigned int* tb = (const unsigned int*)(ws + XBT_OFF) +
                             ((size_t)b * 64 + j * 4) * 4096;

    for (int it = 0; it < 4; ++it) {
        if constexpr (XBT) {
            const unsigned int* src = tb + it * 4096;
#pragma unroll
            for (int rep = 0; rep < 4; ++rep) {
                const int dw = rep * 1024 + tid * 4;
                *reinterpret_cast<uint4*>(&xsd[dw]) =
                    *reinterpret_cast<const uint4*>(src + dw);
            }
        } else {
            stage_xT(xc + it * TN, xsd, tid);
        }
        __syncthreads();

        f32x4 acc[2][4] = {};
#pragma unroll
        for (int kt = 0; kt < 4; ++kt) {
#pragma unroll
            for (int tn = 0; tn < 4; ++tn) {
                const int nl = 16 * tn + m;
                s16x8 bfr;
                if constexpr (XBT) {
                    const int idx = nl * 64 + ((16 * kt + 4 * hq) ^ ((nl & 7) << 2));
                    bfr = __builtin_bit_cast(
                        s16x8, *reinterpret_cast<const int4*>(&xsd[idx]));
                } else {
                    bfr = ld_frag_lds(xsd, nl * 65 + 16 * kt + 4 * hq);
                }
#pragma unroll
                for (int tm = 0; tm < 2; ++tm)
                    acc[tm][tn] = __builtin_amdgcn_mfma_f32_16x16x32_bf16(
                        afr[tm][kt], bfr, acc[tm][tn], 0, 0, 0);
            }
        }
#pragma unroll
        for (int tm = 0; tm < 2; ++tm)
#pragma unroll
            for (int tn = 0; tn < 4; ++tn)
#pragma unroll
                for (int r = 0; r < 4; ++r)
                    oc[(size_t)(32 * w + 16 * tm + 4 * hq + r) * NTOT +
                       it * TN + 16 * tn + m] = acc[tm][tn][r] + bias[tm][r];
        __syncthreads();
    }
}

extern "C" void kernel_launch(void* const* d_in, const int* in_sizes, int n_in,
                              void* d_out, int out_size, void* d_ws, size_t ws_size,
                              hipStream_t stream) {
    const float* x    = (const float*)d_in[0];
    const float* wqkv = (const float*)d_in[1];
    const float* wout = (const float*)d_in[2];
    const float* bout = (const float*)d_in[3];
    float* out = (float*)d_out;
    float* ws  = (float*)d_ws;

    const bool xbt = ws_size >= NEED_BYTES;

    if (xbt)
        k1_ctx<true><<<dim3(NCH, BATCH), 256, 0, stream>>>(x, wqkv, ws);
    else
        k1_ctx<false><<<dim3(NCH, BATCH), 256, 0, stream>>>(x, wqkv, ws);

    k2a_ctx<<<BATCH * 4, 256, 0, stream>>>(ws);
    k2b_buildM<<<dim3(4, BATCH), 256, 0, stream>>>(wqkv, wout, ws);

    if (xbt)
        k3_final<true><<<dim3(NCH3, BATCH), 256, 0, stream>>>(x, bout, ws, out);
    else
        k3_final<false><<<dim3(NCH3, BATCH), 256, 0, stream>>>(x, bout, ws, out);
}

// Round 11
// 116.887 us; speedup vs baseline: 1.0034x; 1.0034x over previous
//
#include <hip/hip_runtime.h>
#include <hip/hip_bf16.h>
#include <math.h>

#define BATCH 32
#define CDIM  128
#define NTOT  4096
#define NCH   32           // k1 chunks per batch (grid 1024)
#define CHN   128          // n per k1 block
#define TN    64           // n per subtile
#define NCH3  16           // k3 chunks per batch

typedef __attribute__((ext_vector_type(4))) float f32x4;
typedef __attribute__((ext_vector_type(8))) short s16x8;

// ---- ws layout (float offsets) ----
#define PC_OFF  0
#define PC_SIZE (BATCH * 4 * NCH * 32 * 32)   // 4,194,304 f
#define PS_OFF  (PC_OFF + PC_SIZE)
#define PS_SIZE (BATCH * 4 * NCH * 32)        // 131,072 f
#define MBF_OFF (PS_OFF + PS_SIZE)
#define MBF_SIZE (BATCH * CDIM * CDIM / 2)    // 262,144 f
#define CTX_OFF (MBF_OFF + MBF_SIZE)
#define CTX_SIZE (BATCH * 4 * 1024)           // 131,072 f
#define XBT_OFF (CTX_OFF + CTX_SIZE)
#define XBT_SIZE (BATCH * CDIM * NTOT / 2)    // 8,388,608 f
#define NEED_BYTES ((size_t)(XBT_OFF + XBT_SIZE) * 4)   // ~52.4 MB

static __device__ __forceinline__ unsigned short f2bf(float f) {
    return __builtin_bit_cast(unsigned short, __float2bfloat16(f));
}
static __device__ __forceinline__ unsigned int pack2(float a, float b) {
    return (unsigned int)f2bf(a) | ((unsigned int)f2bf(b) << 16);
}
static __device__ __forceinline__ s16x8 ld_frag_lds(const unsigned int* p, int d0) {
    int4 t;
    t.x = (int)p[d0]; t.y = (int)p[d0 + 1];
    t.z = (int)p[d0 + 2]; t.w = (int)p[d0 + 3];
    return __builtin_bit_cast(s16x8, t);
}

// staging: fp32 tile -> LDS bf16 [n][c], 65 dw rows (R5/R6-verified)
static __device__ __forceinline__ void stage_xT(const float* __restrict__ xc,
                                                unsigned int* __restrict__ xsd,
                                                int tid) {
    const int m  = tid & 15;
    const int cg = tid >> 4;
#pragma unroll
    for (int p = 0; p < 4; ++p) {
        const int c = 2 * cg + 32 * p;
        const f32x4 a0 = *reinterpret_cast<const f32x4*>(xc + (size_t)c * NTOT + 4 * m);
        const f32x4 a1 = *reinterpret_cast<const f32x4*>(xc + (size_t)(c + 1) * NTOT + 4 * m);
#pragma unroll
        for (int jj = 0; jj < 4; ++jj)
            xsd[(4 * m + jj) * 65 + (c >> 1)] = pack2(a0[jj], a1[jj]);
    }
}

// ---------------------------------------------------------------------------
// k1: KV = W_kv @ x_chunk (MFMA), exp, partial s/C2.
// NCH=32 grid 1024 (supply 4 blocks/CU) + ekv stride 72 (aligned b128 ctx
// reads -> R6's 116-VGPR codegen) + launch_bounds(256,4) pins VGPR<=128
// -> 3 blocks/CU resident (LDS 53.5 KB). 2 barriers/subtile (R9-validated).
// ---------------------------------------------------------------------------
template <bool XBT>
__global__ __launch_bounds__(256, 4)
void k1_ctx(const float* __restrict__ x, const float* __restrict__ wqkv,
            float* __restrict__ ws) {
    __shared__ __attribute__((aligned(16))) unsigned short xsT[64 * 130];    // 16,640 B
    __shared__ __attribute__((aligned(16))) unsigned short ekv[8 * 32 * 72]; // 36,864 B

    const int j = blockIdx.x, b = blockIdx.y;
    const int tid = threadIdx.x;
    const int l = tid & 63;
    const int w = tid >> 6;
    const int m = l & 15, hq = l >> 4;

    // persistent A fragments: W_kv rows 128 + 64w + 16tm + m, k = 32kt + 8hq
    s16x8 afr[4][4];
#pragma unroll
    for (int tm = 0; tm < 4; ++tm)
#pragma unroll
        for (int kt = 0; kt < 4; ++kt) {
            const float* wr = wqkv +
                (size_t)(CDIM + 64 * w + 16 * tm + m) * CDIM + 32 * kt + 8 * hq;
            const f32x4 u0 = *reinterpret_cast<const f32x4*>(wr);
            const f32x4 u1 = *reinterpret_cast<const f32x4*>(wr + 4);
            int4 t4;
            t4.x = (int)pack2(u0[0], u0[1]); t4.y = (int)pack2(u0[2], u0[3]);
            t4.z = (int)pack2(u1[0], u1[1]); t4.w = (int)pack2(u1[2], u1[3]);
            afr[tm][kt] = __builtin_bit_cast(s16x8, t4);
        }

    f32x4 cacc[2][2] = {};
    float sacc[4][4] = {};
    const float* xc = x + (size_t)b * CDIM * NTOT + j * CHN;
    unsigned int* xsd = (unsigned int*)xsT;

    for (int it = 0; it < CHN / TN; ++it) {
        stage_xT(xc + it * TN, xsd, tid);   // global -> LDS (TLP hides latency)
        __syncthreads();                    // S1: xsT ready

        // KV GEMM
        f32x4 acc[4][4] = {};
#pragma unroll
        for (int kt = 0; kt < 4; ++kt) {
#pragma unroll
            for (int tn = 0; tn < 4; ++tn) {
                const s16x8 bfr = ld_frag_lds(xsd, (16 * tn + m) * 65 + 16 * kt + 4 * hq);
#pragma unroll
                for (int tm = 0; tm < 4; ++tm)
                    acc[tm][tn] = __builtin_amdgcn_mfma_f32_16x16x32_bf16(
                        afr[tm][kt], bfr, acc[tm][tn], 0, 0, 0);
            }
        }

        // persist swizzled bf16 tile for k3 (tile = b*64 + j*2 + it)
        if constexpr (XBT) {
            unsigned int* tb = (unsigned int*)(ws + XBT_OFF) +
                               ((size_t)b * 64 + j * 2 + it) * 4096;
            const int n = tid >> 2, qt = tid & 3;
#pragma unroll
            for (int p = 0; p < 4; ++p) {
                const int cdl = 16 * p + 4 * qt;
                const int src = n * 65 + (cdl ^ ((n & 7) << 2));
                uint4 v;
                v.x = xsd[src]; v.y = xsd[src + 1];
                v.z = xsd[src + 2]; v.w = xsd[src + 3];
                *reinterpret_cast<uint4*>(tb + (size_t)n * 64 + cdl) = v;
            }
        }

        // exp(K) -> ekv groups 0..3, V -> groups 4..7 (row stride 72 bf16)
        if (w < 2) {
#pragma unroll
            for (int tm = 0; tm < 4; ++tm)
#pragma unroll
                for (int tn = 0; tn < 4; ++tn)
#pragma unroll
                    for (int r = 0; r < 4; ++r) {
                        const int dg = 64 * w + 16 * tm + 4 * hq + r;
                        const float e = __expf(acc[tm][tn][r]);
                        sacc[tm][r] += e;
                        ekv[((dg >> 5) * 32 + (dg & 31)) * 72 + 16 * tn + m] = f2bf(e);
                    }
        } else {
#pragma unroll
            for (int tm = 0; tm < 4; ++tm)
#pragma unroll
                for (int tn = 0; tn < 4; ++tn)
#pragma unroll
                    for (int r = 0; r < 4; ++r) {
                        const int eg = 64 * (w - 2) + 16 * tm + 4 * hq + r;
                        ekv[((4 + (eg >> 5)) * 32 + (eg & 31)) * 72 + 16 * tn + m] =
                            f2bf(acc[tm][tn][r]);
                    }
        }
        __syncthreads();                 // S2: ekv ready, xsT reads done

        // context MFMA: head = w; aligned b128 reads (row = 36 dwords)
#pragma unroll
        for (int kt = 0; kt < 2; ++kt) {
            s16x8 va[2], eb[2];
#pragma unroll
            for (int t = 0; t < 2; ++t) {
                va[t] = *reinterpret_cast<const s16x8*>(
                    &ekv[((4 + w) * 32 + 16 * t + m) * 72 + 32 * kt + 8 * hq]);
                eb[t] = *reinterpret_cast<const s16x8*>(
                    &ekv[(w * 32 + 16 * t + m) * 72 + 32 * kt + 8 * hq]);
            }
#pragma unroll
            for (int tm = 0; tm < 2; ++tm)
#pragma unroll
                for (int tn = 0; tn < 2; ++tn)
                    cacc[tm][tn] = __builtin_amdgcn_mfma_f32_16x16x32_bf16(
                        va[tm], eb[tn], cacc[tm][tn], 0, 0, 0);
        }
        // next iter's stage_xT is WAR-safe: all xsT readers passed S2
    }

    float* pc = ws + PC_OFF + (size_t)((b * 4 + w) * NCH + j) * 1024;
#pragma unroll
    for (int tm = 0; tm < 2; ++tm)
#pragma unroll
        for (int tn = 0; tn < 2; ++tn)
#pragma unroll
            for (int r = 0; r < 4; ++r)
                pc[(16 * tm + 4 * hq + r) * 32 + 16 * tn + m] = cacc[tm][tn][r];

    if (w < 2) {
#pragma unroll
        for (int tm = 0; tm < 4; ++tm)
#pragma unroll
            for (int r = 0; r < 4; ++r) {
                float s = sacc[tm][r];
                s += __shfl_xor(s, 1);
                s += __shfl_xor(s, 2);
                s += __shfl_xor(s, 4);
                s += __shfl_xor(s, 8);
                if (m == 0) {
                    const int dg = 64 * w + 16 * tm + 4 * hq + r;
                    ws[PS_OFF + (size_t)((b * 4 + (dg >> 5)) * NCH + j) * 32 + (dg & 31)] = s;
                }
            }
    }
}

// ---------------------------------------------------------------------------
// k2a: merge partials -> normalized ctx. One block per (b,h).
// ---------------------------------------------------------------------------
__global__ __launch_bounds__(256)
void k2a_ctx(float* __restrict__ ws) {
    const int bh = blockIdx.x;
    const int tid = threadIdx.x;
    __shared__ float stotS[32];
    if (tid < 32) {
        float s = 0.f;
        for (int jj = 0; jj < NCH; ++jj)
            s += ws[PS_OFF + (size_t)(bh * NCH + jj) * 32 + tid];
        stotS[tid] = s;
    }
    __syncthreads();
#pragma unroll
    for (int k = 0; k < 4; ++k) {
        const int idx = tid + 256 * k;  // e*32 + d
        float c = 0.f;
        for (int jj = 0; jj < NCH; ++jj)
            c += ws[PC_OFF + (size_t)(bh * NCH + jj) * 1024 + idx];
        ws[CTX_OFF + (size_t)bh * 1024 + idx] = c / stotS[idx & 31];
    }
}

// ---------------------------------------------------------------------------
// k2b: M[b] = W_out . BD(ctx) . W_q -> bf16.  grid (4 o-tiles, 32 batches).
// ---------------------------------------------------------------------------
__global__ __launch_bounds__(256)
void k2b_buildM(const float* __restrict__ wqkv, const float* __restrict__ wout,
                float* __restrict__ ws) {
    const int oq = blockIdx.x;
    const int b  = blockIdx.y;
    const int tid = threadIdx.x;

    __shared__ __attribute__((aligned(16))) float smA[8704];
    __shared__ float G[32][133];
    float* ctxs  = smA;          // [hd][33]
    float* wouts = smA + 4224;   // [o][133]
    unsigned int* wqs = (unsigned int*)smA;  // phase B: [hd][68] dwords

#pragma unroll
    for (int k = 0; k < 16; ++k) {
        const int fid = tid + 256 * k;          // h*1024 + e*32 + d
        const int h = fid >> 10, rem = fid & 1023;
        const int e = rem >> 5, d = rem & 31;
        ctxs[(h * 32 + d) * 33 + e] = ws[CTX_OFF + (size_t)b * 4096 + fid];
    }
#pragma unroll
    for (int k = 0; k < 16; ++k) {
        const int fid = tid + 256 * k;          // o*128 + c
        const int o = fid >> 7, c = fid & 127;
        wouts[o * 133 + c] = wout[(size_t)(oq * 32 + o) * CDIM + c];
    }
    __syncthreads();

    {
        const int o2 = tid & 31;
        const int g8 = tid >> 5;
#pragma unroll
        for (int i = 0; i < 16; ++i) {
            const int hd = g8 * 16 + i;
            const int h = hd >> 5;
            float acc = 0.f;
#pragma unroll
            for (int e = 0; e < 32; ++e)
                acc = fmaf(wouts[o2 * 133 + h * 32 + e], ctxs[hd * 33 + e], acc);
            G[o2][hd] = acc;
        }
    }
    __syncthreads();

    {
#pragma unroll
        for (int k = 0; k < 32; ++k) {
            const int fid = tid + 256 * k;      // hd*64 + cd
            const int hd = fid >> 6, cd = fid & 63;
            const float2 wv =
                *reinterpret_cast<const float2*>(wqkv + (size_t)hd * CDIM + 2 * cd);
            wqs[hd * 68 + cd] = pack2(wv.x, wv.y);
        }
    }
    __syncthreads();

    {
        const int o3 = tid >> 3;
        const int c0 = tid & 7;
        float Macc[16];
#pragma unroll
        for (int i = 0; i < 16; ++i) Macc[i] = 0.f;
        for (int hd = 0; hd < 128; ++hd) {
            const float gv = G[o3][hd];
            const uint4 w0 = *reinterpret_cast<const uint4*>(&wqs[hd * 68 + c0 * 8]);
            const uint4 w1 = *reinterpret_cast<const uint4*>(&wqs[hd * 68 + c0 * 8 + 4]);
            const unsigned int dw[8] = {w0.x, w0.y, w0.z, w0.w, w1.x, w1.y, w1.z, w1.w};
#pragma unroll
            for (int q = 0; q < 8; ++q) {
                const float lo = __builtin_bit_cast(float, dw[q] << 16);
                const float hi = __builtin_bit_cast(float, dw[q] & 0xffff0000u);
                Macc[2 * q]     = fmaf(gv, lo, Macc[2 * q]);
                Macc[2 * q + 1] = fmaf(gv, hi, Macc[2 * q + 1]);
            }
        }
        unsigned int* mpd = (unsigned int*)((unsigned short*)(ws + MBF_OFF) +
                                            (size_t)b * CDIM * CDIM) +
                            (oq * 32 + o3) * 64 + c0 * 8;
        uint4 s0, s1;
        s0.x = pack2(Macc[0], Macc[1]);   s0.y = pack2(Macc[2], Macc[3]);
        s0.z = pack2(Macc[4], Macc[5]);   s0.w = pack2(Macc[6], Macc[7]);
        s1.x = pack2(Macc[8], Macc[9]);   s1.y = pack2(Macc[10], Macc[11]);
        s1.z = pack2(Macc[12], Macc[13]); s1.w = pack2(Macc[14], Macc[15]);
        *reinterpret_cast<uint4*>(mpd) = s0;
        *reinterpret_cast<uint4*>(mpd + 4) = s1;
    }
}

// ---------------------------------------------------------------------------
// k3: out[b] = M_bf16[b] @ x_bf16[b] + b_out.  (R6/R9-verified: plain uint4
// reg-copy of pre-swizzled tiles, 2 syncthreads/iter.)
// ---------------------------------------------------------------------------
template <bool XBT>
__global__ __launch_bounds__(256)
void k3_final(const float* __restrict__ x, const float* __restrict__ bout,
              const float* __restrict__ ws, float* __restrict__ out) {
    __shared__ __attribute__((aligned(16))) unsigned int xsd[4160];

    const int j = blockIdx.x, b = blockIdx.y;
    const int tid = threadIdx.x, l = tid & 63, w = tid >> 6;
    const int m = l & 15, hq = l >> 4;

    const unsigned short* mbf =
        (const unsigned short*)(ws + MBF_OFF) + (size_t)b * CDIM * CDIM;
    s16x8 afr[2][4];
#pragma unroll
    for (int tm = 0; tm < 2; ++tm)
#pragma unroll
        for (int kt = 0; kt < 4; ++kt)
            afr[tm][kt] = *reinterpret_cast<const s16x8*>(
                mbf + (size_t)(32 * w + 16 * tm + m) * CDIM + 32 * kt + 8 * hq);
    float bias[2][4];
#pragma unroll
    for (int tm = 0; tm < 2; ++tm)
#pragma unroll
        for (int r = 0; r < 4; ++r)
            bias[tm][r] = bout[32 * w + 16 * tm + 4 * hq + r];

    const float* xc = x + (size_t)b * CDIM * NTOT + j * 256;
    float* oc = out + (size_t)b * CDIM * NTOT + j * 256;
    const unsigned int* tb = (const unsigned int*)(ws + XBT_OFF) +
                             ((size_t)b * 64 + j * 4) * 4096;

    for (int it = 0; it < 4; ++it) {
        if constexpr (XBT) {
            const unsigned int* src = tb + it * 4096;
#pragma unroll
            for (int rep = 0; rep < 4; ++rep) {
                const int dw = rep * 1024 + tid * 4;
                *reinterpret_cast<uint4*>(&xsd[dw]) =
                    *reinterpret_cast<const uint4*>(src + dw);
            }
        } else {
            stage_xT(xc + it * TN, xsd, tid);
        }
        __syncthreads();

        f32x4 acc[2][4] = {};
#pragma unroll
        for (int kt = 0; kt < 4; ++kt) {
#pragma unroll
            for (int tn = 0; tn < 4; ++tn) {
                const int nl = 16 * tn + m;
                s16x8 bfr;
                if constexpr (XBT) {
                    const int idx = nl * 64 + ((16 * kt + 4 * hq) ^ ((nl & 7) << 2));
                    bfr = __builtin_bit_cast(
                        s16x8, *reinterpret_cast<const int4*>(&xsd[idx]));
                } else {
                    bfr = ld_frag_lds(xsd, nl * 65 + 16 * kt + 4 * hq);
                }
#pragma unroll
                for (int tm = 0; tm < 2; ++tm)
                    acc[tm][tn] = __builtin_amdgcn_mfma_f32_16x16x32_bf16(
                        afr[tm][kt], bfr, acc[tm][tn], 0, 0, 0);
            }
        }
#pragma unroll
        for (int tm = 0; tm < 2; ++tm)
#pragma unroll
            for (int tn = 0; tn < 4; ++tn)
#pragma unroll
                for (int r = 0; r < 4; ++r)
                    oc[(size_t)(32 * w + 16 * tm + 4 * hq + r) * NTOT +
                       it * TN + 16 * tn + m] = acc[tm][tn][r] + bias[tm][r];
        __syncthreads();
    }
}

extern "C" void kernel_launch(void* const* d_in, const int* in_sizes, int n_in,
                              void* d_out, int out_size, void* d_ws, size_t ws_size,
                              hipStream_t stream) {
    const float* x    = (const float*)d_in[0];
    const float* wqkv = (const float*)d_in[1];
    const float* wout = (const float*)d_in[2];
    const float* bout = (const float*)d_in[3];
    float* out = (float*)d_out;
    float* ws  = (float*)d_ws;

    const bool xbt = ws_size >= NEED_BYTES;

    if (xbt)
        k1_ctx<true><<<dim3(NCH, BATCH), 256, 0, stream>>>(x, wqkv, ws);
    else
        k1_ctx<false><<<dim3(NCH, BATCH), 256, 0, stream>>>(x, wqkv, ws);

    k2a_ctx<<<BATCH * 4, 256, 0, stream>>>(ws);
    k2b_buildM<<<dim3(4, BATCH), 256, 0, stream>>>(wqkv, wout, ws);

    if (xbt)
        k3_final<true><<<dim3(NCH3, BATCH), 256, 0, stream>>>(x, bout, ws, out);
    else
        k3_final<false><<<dim3(NCH3, BATCH), 256, 0, stream>>>(x, bout, ws, out);
}

// Round 13
// 113.749 us; speedup vs baseline: 1.0311x; 1.0276x over previous
//
#include <hip/hip_runtime.h>
#include <hip/hip_bf16.h>
#include <math.h>

#define BATCH 32
#define CDIM  128
#define NTOT  4096
#define NCH   32           // k1 chunks per batch (grid 1024)
#define CHN   128          // n per k1 block
#define TN    64           // n per subtile
#define NCH3  16           // k3 chunks per batch

typedef __attribute__((ext_vector_type(4))) float f32x4;
typedef __attribute__((ext_vector_type(8))) short s16x8;

// ---- ws layout (float offsets) ----
#define PC_OFF  0
#define PC_SIZE (BATCH * 4 * NCH * 32 * 32)   // 4,194,304 f
#define PS_OFF  (PC_OFF + PC_SIZE)
#define PS_SIZE (BATCH * 4 * NCH * 32)        // 131,072 f
#define MBF_OFF (PS_OFF + PS_SIZE)
#define MBF_SIZE (BATCH * CDIM * CDIM / 2)    // 262,144 f
#define CTX_OFF (MBF_OFF + MBF_SIZE)
#define CTX_SIZE (BATCH * 4 * 1024)           // 131,072 f
#define WBF_OFF (CTX_OFF + CTX_SIZE)          // w_qkv bf16: 49,152 u16 = 24,576 f
#define WBF_SIZE 24576
#define XBT_OFF (WBF_OFF + WBF_SIZE)
#define XBT_SIZE (BATCH * CDIM * NTOT / 2)    // 8,388,608 f
#define NEED_BYTES ((size_t)(XBT_OFF + XBT_SIZE) * 4)   // ~52.5 MB

static __device__ __forceinline__ unsigned short f2bf(float f) {
    return __builtin_bit_cast(unsigned short, __float2bfloat16(f));
}
static __device__ __forceinline__ unsigned int pack2(float a, float b) {
    return (unsigned int)f2bf(a) | ((unsigned int)f2bf(b) << 16);
}
static __device__ __forceinline__ s16x8 ld_frag_lds(const unsigned int* p, int d0) {
    int4 t;
    t.x = (int)p[d0]; t.y = (int)p[d0 + 1];
    t.z = (int)p[d0 + 2]; t.w = (int)p[d0 + 3];
    return __builtin_bit_cast(s16x8, t);
}

// staging: fp32 tile -> LDS bf16 [n][c], 65 dw rows (R5/R6-verified)
static __device__ __forceinline__ void stage_xT(const float* __restrict__ xc,
                                                unsigned int* __restrict__ xsd,
                                                int tid) {
    const int m  = tid & 15;
    const int cg = tid >> 4;
#pragma unroll
    for (int p = 0; p < 4; ++p) {
        const int c = 2 * cg + 32 * p;
        const f32x4 a0 = *reinterpret_cast<const f32x4*>(xc + (size_t)c * NTOT + 4 * m);
        const f32x4 a1 = *reinterpret_cast<const f32x4*>(xc + (size_t)(c + 1) * NTOT + 4 * m);
#pragma unroll
        for (int jj = 0; jj < 4; ++jj)
            xsd[(4 * m + jj) * 65 + (c >> 1)] = pack2(a0[jj], a1[jj]);
    }
}

// ---------------------------------------------------------------------------
// k0: convert w_qkv to bf16 in ws (R6-verified; keeps k1's W loads as plain
// s16x8 -> VGPR ~116, under the 128 occupancy cliff)
// ---------------------------------------------------------------------------
__global__ void k0_wcvt(const float* __restrict__ wqkv, float* __restrict__ ws) {
    const int i = blockIdx.x * 256 + threadIdx.x;
    unsigned short* wbf = (unsigned short*)(ws + WBF_OFF);
    if (i < 384 * CDIM) wbf[i] = f2bf(wqkv[i]);
}

// ---------------------------------------------------------------------------
// k1: KV = W_kv @ x_chunk (MFMA), exp, partial s/C2.
// R6 codegen (wbf fragment loads, VGPR ~116 -> 4 waves/SIMD budget)
// + NCH=32 grid 1024 + LDS 53.76 KB -> 3 blocks/CU resident.
// 2 barriers/subtile (R11-verified), stride-72 aligned ekv b128 reads.
// ---------------------------------------------------------------------------
template <bool XBT>
__global__ __launch_bounds__(256)
void k1_ctx(const float* __restrict__ x, const unsigned short* __restrict__ wbf,
            float* __restrict__ ws) {
    __shared__ __attribute__((aligned(16))) unsigned short xsT[64 * 130];    // 16,640 B
    __shared__ __attribute__((aligned(16))) unsigned short ekv[8 * 32 * 72]; // 36,864 B

    const int j = blockIdx.x, b = blockIdx.y;
    const int tid = threadIdx.x;
    const int l = tid & 63;
    const int w = tid >> 6;
    const int m = l & 15, hq = l >> 4;

    // persistent A fragments: W_kv rows 128 + 64w + 16tm + m, k = 32kt + 8hq
    s16x8 afr[4][4];
#pragma unroll
    for (int tm = 0; tm < 4; ++tm)
#pragma unroll
        for (int kt = 0; kt < 4; ++kt)
            afr[tm][kt] = *reinterpret_cast<const s16x8*>(
                wbf + (size_t)(CDIM + 64 * w + 16 * tm + m) * CDIM + 32 * kt + 8 * hq);

    f32x4 cacc[2][2] = {};
    float sacc[4][4] = {};
    const float* xc = x + (size_t)b * CDIM * NTOT + j * CHN;
    unsigned int* xsd = (unsigned int*)xsT;

    for (int it = 0; it < CHN / TN; ++it) {
        stage_xT(xc + it * TN, xsd, tid);   // global -> LDS (TLP hides latency)
        __syncthreads();                    // S1: xsT ready

        // KV GEMM
        f32x4 acc[4][4] = {};
#pragma unroll
        for (int kt = 0; kt < 4; ++kt) {
#pragma unroll
            for (int tn = 0; tn < 4; ++tn) {
                const s16x8 bfr = ld_frag_lds(xsd, (16 * tn + m) * 65 + 16 * kt + 4 * hq);
#pragma unroll
                for (int tm = 0; tm < 4; ++tm)
                    acc[tm][tn] = __builtin_amdgcn_mfma_f32_16x16x32_bf16(
                        afr[tm][kt], bfr, acc[tm][tn], 0, 0, 0);
            }
        }

        // persist swizzled bf16 tile for k3 (tile = b*64 + j*2 + it)
        if constexpr (XBT) {
            unsigned int* tb = (unsigned int*)(ws + XBT_OFF) +
                               ((size_t)b * 64 + j * 2 + it) * 4096;
            const int n = tid >> 2, qt = tid & 3;
#pragma unroll
            for (int p = 0; p < 4; ++p) {
                const int cdl = 16 * p + 4 * qt;
                const int src = n * 65 + (cdl ^ ((n & 7) << 2));
                uint4 v;
                v.x = xsd[src]; v.y = xsd[src + 1];
                v.z = xsd[src + 2]; v.w = xsd[src + 3];
                *reinterpret_cast<uint4*>(tb + (size_t)n * 64 + cdl) = v;
            }
        }

        // exp(K) -> ekv groups 0..3, V -> groups 4..7 (row stride 72 bf16)
        if (w < 2) {
#pragma unroll
            for (int tm = 0; tm < 4; ++tm)
#pragma unroll
                for (int tn = 0; tn < 4; ++tn)
#pragma unroll
                    for (int r = 0; r < 4; ++r) {
                        const int dg = 64 * w + 16 * tm + 4 * hq + r;
                        const float e = __expf(acc[tm][tn][r]);
                        sacc[tm][r] += e;
                        ekv[((dg >> 5) * 32 + (dg & 31)) * 72 + 16 * tn + m] = f2bf(e);
                    }
        } else {
#pragma unroll
            for (int tm = 0; tm < 4; ++tm)
#pragma unroll
                for (int tn = 0; tn < 4; ++tn)
#pragma unroll
                    for (int r = 0; r < 4; ++r) {
                        const int eg = 64 * (w - 2) + 16 * tm + 4 * hq + r;
                        ekv[((4 + (eg >> 5)) * 32 + (eg & 31)) * 72 + 16 * tn + m] =
                            f2bf(acc[tm][tn][r]);
                    }
        }
        __syncthreads();                 // S2: ekv ready, xsT reads done

        // context MFMA: head = w; aligned b128 reads (row = 36 dwords)
#pragma unroll
        for (int kt = 0; kt < 2; ++kt) {
            s16x8 va[2], eb[2];
#pragma unroll
            for (int t = 0; t < 2; ++t) {
                va[t] = *reinterpret_cast<const s16x8*>(
                    &ekv[((4 + w) * 32 + 16 * t + m) * 72 + 32 * kt + 8 * hq]);
                eb[t] = *reinterpret_cast<const s16x8*>(
                    &ekv[(w * 32 + 16 * t + m) * 72 + 32 * kt + 8 * hq]);
            }
#pragma unroll
            for (int tm = 0; tm < 2; ++tm)
#pragma unroll
                for (int tn = 0; tn < 2; ++tn)
                    cacc[tm][tn] = __builtin_amdgcn_mfma_f32_16x16x32_bf16(
                        va[tm], eb[tn], cacc[tm][tn], 0, 0, 0);
        }
        // next iter's stage_xT is WAR-safe: all xsT readers passed S2
    }

    float* pc = ws + PC_OFF + (size_t)((b * 4 + w) * NCH + j) * 1024;
#pragma unroll
    for (int tm = 0; tm < 2; ++tm)
#pragma unroll
        for (int tn = 0; tn < 2; ++tn)
#pragma unroll
            for (int r = 0; r < 4; ++r)
                pc[(16 * tm + 4 * hq + r) * 32 + 16 * tn + m] = cacc[tm][tn][r];

    if (w < 2) {
#pragma unroll
        for (int tm = 0; tm < 4; ++tm)
#pragma unroll
            for (int r = 0; r < 4; ++r) {
                float s = sacc[tm][r];
                s += __shfl_xor(s, 1);
                s += __shfl_xor(s, 2);
                s += __shfl_xor(s, 4);
                s += __shfl_xor(s, 8);
                if (m == 0) {
                    const int dg = 64 * w + 16 * tm + 4 * hq + r;
                    ws[PS_OFF + (size_t)((b * 4 + (dg >> 5)) * NCH + j) * 32 + (dg & 31)] = s;
                }
            }
    }
}

// ---------------------------------------------------------------------------
// k2a: merge partials -> normalized ctx. One block per (b,h).
// ---------------------------------------------------------------------------
__global__ __launch_bounds__(256)
void k2a_ctx(float* __restrict__ ws) {
    const int bh = blockIdx.x;
    const int tid = threadIdx.x;
    __shared__ float stotS[32];
    if (tid < 32) {
        float s = 0.f;
        for (int jj = 0; jj < NCH; ++jj)
            s += ws[PS_OFF + (size_t)(bh * NCH + jj) * 32 + tid];
        stotS[tid] = s;
    }
    __syncthreads();
#pragma unroll
    for (int k = 0; k < 4; ++k) {
        const int idx = tid + 256 * k;  // e*32 + d
        float c = 0.f;
        for (int jj = 0; jj < NCH; ++jj)
            c += ws[PC_OFF + (size_t)(bh * NCH + jj) * 1024 + idx];
        ws[CTX_OFF + (size_t)bh * 1024 + idx] = c / stotS[idx & 31];
    }
}

// ---------------------------------------------------------------------------
// k2b: M[b] = W_out . BD(ctx) . W_q -> bf16.  grid (4 o-tiles, 32 batches).
// ---------------------------------------------------------------------------
__global__ __launch_bounds__(256)
void k2b_buildM(const float* __restrict__ wqkv, const float* __restrict__ wout,
                float* __restrict__ ws) {
    const int oq = blockIdx.x;
    const int b  = blockIdx.y;
    const int tid = threadIdx.x;

    __shared__ __attribute__((aligned(16))) float smA[8704];
    __shared__ float G[32][133];
    float* ctxs  = smA;          // [hd][33]
    float* wouts = smA + 4224;   // [o][133]
    unsigned int* wqs = (unsigned int*)smA;  // phase B: [hd][68] dwords

#pragma unroll
    for (int k = 0; k < 16; ++k) {
        const int fid = tid + 256 * k;          // h*1024 + e*32 + d
        const int h = fid >> 10, rem = fid & 1023;
        const int e = rem >> 5, d = rem & 31;
        ctxs[(h * 32 + d) * 33 + e] = ws[CTX_OFF + (size_t)b * 4096 + fid];
    }
#pragma unroll
    for (int k = 0; k < 16; ++k) {
        const int fid = tid + 256 * k;          // o*128 + c
        const int o = fid >> 7, c = fid & 127;
        wouts[o * 133 + c] = wout[(size_t)(oq * 32 + o) * CDIM + c];
    }
    __syncthreads();

    {
        const int o2 = tid & 31;
        const int g8 = tid >> 5;
#pragma unroll
        for (int i = 0; i < 16; ++i) {
            const int hd = g8 * 16 + i;
            const int h = hd >> 5;
            float acc = 0.f;
#pragma unroll
            for (int e = 0; e < 32; ++e)
                acc = fmaf(wouts[o2 * 133 + h * 32 + e], ctxs[hd * 33 + e], acc);
            G[o2][hd] = acc;
        }
    }
    __syncthreads();

    {
#pragma unroll
        for (int k = 0; k < 32; ++k) {
            const int fid = tid + 256 * k;      // hd*64 + cd
            const int hd = fid >> 6, cd = fid & 63;
            const float2 wv =
                *reinterpret_cast<const float2*>(wqkv + (size_t)hd * CDIM + 2 * cd);
            wqs[hd * 68 + cd] = pack2(wv.x, wv.y);
        }
    }
    __syncthreads();

    {
        const int o3 = tid >> 3;
        const int c0 = tid & 7;
        float Macc[16];
#pragma unroll
        for (int i = 0; i < 16; ++i) Macc[i] = 0.f;
        for (int hd = 0; hd < 128; ++hd) {
            const float gv = G[o3][hd];
            const uint4 w0 = *reinterpret_cast<const uint4*>(&wqs[hd * 68 + c0 * 8]);
            const uint4 w1 = *reinterpret_cast<const uint4*>(&wqs[hd * 68 + c0 * 8 + 4]);
            const unsigned int dw[8] = {w0.x, w0.y, w0.z, w0.w, w1.x, w1.y, w1.z, w1.w};
#pragma unroll
            for (int q = 0; q < 8; ++q) {
                const float lo = __builtin_bit_cast(float, dw[q] << 16);
                const float hi = __builtin_bit_cast(float, dw[q] & 0xffff0000u);
                Macc[2 * q]     = fmaf(gv, lo, Macc[2 * q]);
                Macc[2 * q + 1] = fmaf(gv, hi, Macc[2 * q + 1]);
            }
        }
        unsigned int* mpd = (unsigned int*)((unsigned short*)(ws + MBF_OFF) +
                                            (size_t)b * CDIM * CDIM) +
                            (oq * 32 + o3) * 64 + c0 * 8;
        uint4 s0, s1;
        s0.x = pack2(Macc[0], Macc[1]);   s0.y = pack2(Macc[2], Macc[3]);
        s0.z = pack2(Macc[4], Macc[5]);   s0.w = pack2(Macc[6], Macc[7]);
        s1.x = pack2(Macc[8], Macc[9]);   s1.y = pack2(Macc[10], Macc[11]);
        s1.z = pack2(Macc[12], Macc[13]); s1.w = pack2(Macc[14], Macc[15]);
        *reinterpret_cast<uint4*>(mpd) = s0;
        *reinterpret_cast<uint4*>(mpd + 4) = s1;
    }
}

// ---------------------------------------------------------------------------
// k3: out[b] = M_bf16[b] @ x_bf16[b] + b_out.  (R6/R9-verified: plain uint4
// reg-copy of pre-swizzled tiles, 2 syncthreads/iter.)
// ---------------------------------------------------------------------------
template <bool XBT>
__global__ __launch_bounds__(256)
void k3_final(const float* __restrict__ x, const float* __restrict__ bout,
              const float* __restrict__ ws, float* __restrict__ out) {
    __shared__ __attribute__((aligned(16))) unsigned int xsd[4160];

    const int j = blockIdx.x, b = blockIdx.y;
    const int tid = threadIdx.x, l = tid & 63, w = tid >> 6;
    const int m = l & 15, hq = l >> 4;

    const unsigned short* mbf =
        (const unsigned short*)(ws + MBF_OFF) + (size_t)b * CDIM * CDIM;
    s16x8 afr[2][4];
#pragma unroll
    for (int tm = 0; tm < 2; ++tm)
#pragma unroll
        for (int kt = 0; kt < 4; ++kt)
            afr[tm][kt] = *reinterpret_cast<const s16x8*>(
                mbf + (size_t)(32 * w + 16 * tm + m) * CDIM + 32 * kt + 8 * hq);
    float bias[2][4];
#pragma unroll
    for (int tm = 0; tm < 2; ++tm)
#pragma unroll
        for (int r = 0; r < 4; ++r)
            bias[tm][r] = bout[32 * w + 16 * tm + 4 * hq + r];

    const float* xc = x + (size_t)b * CDIM * NTOT + j * 256;
    float* oc = out + (size_t)b * CDIM * NTOT + j * 256;
    const unsigned int* tb = (const unsigned int*)(ws + XBT_OFF) +
                             ((size_t)b * 64 + j * 4) * 4096;

    for (int it = 0; it < 4; ++it) {
        if constexpr (XBT) {
            const unsigned int* src = tb + it * 4096;
#pragma unroll
            for (int rep = 0; rep < 4; ++rep) {
                const int dw = rep * 1024 + tid * 4;
                *reinterpret_cast<uint4*>(&xsd[dw]) =
                    *reinterpret_cast<const uint4*>(src + dw);
            }
        } else {
            stage_xT(xc + it * TN, xsd, tid);
        }
        __syncthreads();

        f32x4 acc[2][4] = {};
#pragma unroll
        for (int kt = 0; kt < 4; ++kt) {
#pragma unroll
            for (int tn = 0; tn < 4; ++tn) {
                const int nl = 16 * tn + m;
                s16x8 bfr;
                if constexpr (XBT) {
                    const int idx = nl * 64 + ((16 * kt + 4 * hq) ^ ((nl & 7) << 2));
                    bfr = __builtin_bit_cast(
                        s16x8, *reinterpret_cast<const int4*>(&xsd[idx]));
                } else {
                    bfr = ld_frag_lds(xsd, nl * 65 + 16 * kt + 4 * hq);
                }
#pragma unroll
                for (int tm = 0; tm < 2; ++tm)
                    acc[tm][tn] = __builtin_amdgcn_mfma_f32_16x16x32_bf16(
                        afr[tm][kt], bfr, acc[tm][tn], 0, 0, 0);
            }
        }
#pragma unroll
        for (int tm = 0; tm < 2; ++tm)
#pragma unroll
            for (int tn = 0; tn < 4; ++tn)
#pragma unroll
                for (int r = 0; r < 4; ++r)
                    oc[(size_t)(32 * w + 16 * tm + 4 * hq + r) * NTOT +
                       it * TN + 16 * tn + m] = acc[tm][tn][r] + bias[tm][r];
        __syncthreads();
    }
}

extern "C" void kernel_launch(void* const* d_in, const int* in_sizes, int n_in,
                              void* d_out, int out_size, void* d_ws, size_t ws_size,
                              hipStream_t stream) {
    const float* x    = (const float*)d_in[0];
    const float* wqkv = (const float*)d_in[1];
    const float* wout = (const float*)d_in[2];
    const float* bout = (const float*)d_in[3];
    float* out = (float*)d_out;
    float* ws  = (float*)d_ws;

    const bool xbt = ws_size >= NEED_BYTES;
    const unsigned short* wbf = (const unsigned short*)(ws + WBF_OFF);

    k0_wcvt<<<192, 256, 0, stream>>>(wqkv, ws);

    if (xbt)
        k1_ctx<true><<<dim3(NCH, BATCH), 256, 0, stream>>>(x, wbf, ws);
    else
        k1_ctx<false><<<dim3(NCH, BATCH), 256, 0, stream>>>(x, wbf, ws);

    k2a_ctx<<<BATCH * 4, 256, 0, stream>>>(ws);
    k2b_buildM<<<dim3(4, BATCH), 256, 0, stream>>>(wqkv, wout, ws);

    if (xbt)
        k3_final<true><<<dim3(NCH3, BATCH), 256, 0, stream>>>(x, bout, ws, out);
    else
        k3_final<false><<<dim3(NCH3, BATCH), 256, 0, stream>>>(x, bout, ws, out);
}

// Round 14
// 87.929 us; speedup vs baseline: 1.3338x; 1.2936x over previous
//
#include <hip/hip_runtime.h>
#include <hip/hip_bf16.h>
#include <math.h>

#define BATCH 32
#define CDIM  128
#define NTOT  4096
#define NCH   32           // k1 chunks per batch (grid 1024)
#define CHN   128          // n per k1 block
#define TN    64           // n per subtile
#define NCH3  16           // k3 chunks per batch

typedef __attribute__((ext_vector_type(4))) float f32x4;
typedef __attribute__((ext_vector_type(8))) short s16x8;

// ---- ws layout (float offsets) ----
#define PC_OFF  0
#define PC_SIZE (BATCH * 4 * NCH * 32 * 32)   // 4,194,304 f
#define PS_OFF  (PC_OFF + PC_SIZE)
#define PS_SIZE (BATCH * 4 * NCH * 32)        // 131,072 f
#define MBF_OFF (PS_OFF + PS_SIZE)
#define MBF_SIZE (BATCH * CDIM * CDIM / 2)    // 262,144 f
#define CTX_OFF (MBF_OFF + MBF_SIZE)
#define CTX_SIZE (BATCH * 4 * 1024)           // 131,072 f
#define XBT_OFF (CTX_OFF + CTX_SIZE)
#define XBT_SIZE (BATCH * CDIM * NTOT / 2)    // 8,388,608 f
#define NEED_BYTES ((size_t)(XBT_OFF + XBT_SIZE) * 4)   // ~52.4 MB

static __device__ __forceinline__ unsigned short f2bf(float f) {
    return __builtin_bit_cast(unsigned short, __float2bfloat16(f));
}
static __device__ __forceinline__ unsigned int pack2(float a, float b) {
    return (unsigned int)f2bf(a) | ((unsigned int)f2bf(b) << 16);
}
static __device__ __forceinline__ s16x8 ld_frag_lds(const unsigned int* p, int d0) {
    int4 t;
    t.x = (int)p[d0]; t.y = (int)p[d0 + 1];
    t.z = (int)p[d0 + 2]; t.w = (int)p[d0 + 3];
    return __builtin_bit_cast(s16x8, t);
}

// staging: fp32 tile -> LDS bf16 [n][c], 65 dw rows (R5/R6-verified)
static __device__ __forceinline__ void stage_xT(const float* __restrict__ xc,
                                                unsigned int* __restrict__ xsd,
                                                int tid) {
    const int m  = tid & 15;
    const int cg = tid >> 4;
#pragma unroll
    for (int p = 0; p < 4; ++p) {
        const int c = 2 * cg + 32 * p;
        const f32x4 a0 = *reinterpret_cast<const f32x4*>(xc + (size_t)c * NTOT + 4 * m);
        const f32x4 a1 = *reinterpret_cast<const f32x4*>(xc + (size_t)(c + 1) * NTOT + 4 * m);
#pragma unroll
        for (int jj = 0; jj < 4; ++jj)
            xsd[(4 * m + jj) * 65 + (c >> 1)] = pack2(a0[jj], a1[jj]);
    }
}

// ---------------------------------------------------------------------------
// k1: EXACT R6 structure (inline W cvt, 3D ekv pad-72, THREE barriers,
// launch_bounds(256,2) -> VGPR ~116 codegen: the loop-end barrier fences the
// compiler's load-hoisting that inflated VGPR to 152 in R9-R13).
// Only delta vs R6: NCH=32 (grid 1024) -> 3 blocks/CU resident (LDS 53.5 KB).
// ---------------------------------------------------------------------------
template <bool XBT>
__global__ __launch_bounds__(256, 2)
void k1_ctx(const float* __restrict__ x, const float* __restrict__ wqkv,
            float* __restrict__ ws) {
    __shared__ __attribute__((aligned(16))) unsigned short xsT[64 * 130];   // 16.6 KB
    __shared__ __attribute__((aligned(16))) unsigned short ekv[8][32][72];  // 36.9 KB

    const int j = blockIdx.x, b = blockIdx.y;
    const int tid = threadIdx.x;
    const int l = tid & 63;
    const int w = tid >> 6;
    const int m = l & 15, hq = l >> 4;

    // persistent A fragments: W_kv rows 128 + 64w + 16tm + m, k = 32kt + 8hq
    // inline fp32->bf16 (bitwise same as k0 conversion)
    s16x8 afr[4][4];
#pragma unroll
    for (int tm = 0; tm < 4; ++tm)
#pragma unroll
        for (int kt = 0; kt < 4; ++kt) {
            const float* wr = wqkv +
                (size_t)(CDIM + 64 * w + 16 * tm + m) * CDIM + 32 * kt + 8 * hq;
            const f32x4 u0 = *reinterpret_cast<const f32x4*>(wr);
            const f32x4 u1 = *reinterpret_cast<const f32x4*>(wr + 4);
            int4 t4;
            t4.x = (int)pack2(u0[0], u0[1]); t4.y = (int)pack2(u0[2], u0[3]);
            t4.z = (int)pack2(u1[0], u1[1]); t4.w = (int)pack2(u1[2], u1[3]);
            afr[tm][kt] = __builtin_bit_cast(s16x8, t4);
        }

    f32x4 cacc[2][2] = {};
    float sacc[4][4] = {};
    const float* xc = x + (size_t)b * CDIM * NTOT + j * CHN;
    unsigned int* xsd = (unsigned int*)xsT;

    for (int it = 0; it < CHN / TN; ++it) {
        stage_xT(xc + it * TN, xsd, tid);
        __syncthreads();  // S1: xsT ready

        // KV GEMM
        f32x4 acc[4][4] = {};
#pragma unroll
        for (int kt = 0; kt < 4; ++kt) {
#pragma unroll
            for (int tn = 0; tn < 4; ++tn) {
                const s16x8 bfr = ld_frag_lds(xsd, (16 * tn + m) * 65 + 16 * kt + 4 * hq);
#pragma unroll
                for (int tm = 0; tm < 4; ++tm)
                    acc[tm][tn] = __builtin_amdgcn_mfma_f32_16x16x32_bf16(
                        afr[tm][kt], bfr, acc[tm][tn], 0, 0, 0);
            }
        }

        // persist swizzled bf16 tile for k3 (tile = b*64 + j*2 + it)
        if constexpr (XBT) {
            unsigned int* tb = (unsigned int*)(ws + XBT_OFF) +
                               ((size_t)b * 64 + j * 2 + it) * 4096;
            const int n = tid >> 2, qt = tid & 3;
#pragma unroll
            for (int p = 0; p < 4; ++p) {
                const int cdl = 16 * p + 4 * qt;
                const int src = n * 65 + (cdl ^ ((n & 7) << 2));
                uint4 v;
                v.x = xsd[src]; v.y = xsd[src + 1];
                v.z = xsd[src + 2]; v.w = xsd[src + 3];
                *reinterpret_cast<uint4*>(tb + (size_t)n * 64 + cdl) = v;
            }
        }

        // exp(K) -> ekv[0..3], V -> ekv[4..7]
        if (w < 2) {
#pragma unroll
            for (int tm = 0; tm < 4; ++tm)
#pragma unroll
                for (int tn = 0; tn < 4; ++tn)
#pragma unroll
                    for (int r = 0; r < 4; ++r) {
                        const int dg = 64 * w + 16 * tm + 4 * hq + r;
                        const float e = __expf(acc[tm][tn][r]);
                        sacc[tm][r] += e;
                        ekv[dg >> 5][dg & 31][16 * tn + m] = f2bf(e);
                    }
        } else {
#pragma unroll
            for (int tm = 0; tm < 4; ++tm)
#pragma unroll
                for (int tn = 0; tn < 4; ++tn)
#pragma unroll
                    for (int r = 0; r < 4; ++r) {
                        const int eg = 64 * (w - 2) + 16 * tm + 4 * hq + r;
                        ekv[4 + (eg >> 5)][eg & 31][16 * tn + m] = f2bf(acc[tm][tn][r]);
                    }
        }
        __syncthreads();  // S2: ekv ready

        // context MFMA: head = w
#pragma unroll
        for (int kt = 0; kt < 2; ++kt) {
            s16x8 va[2], eb[2];
#pragma unroll
            for (int t = 0; t < 2; ++t) {
                va[t] = *reinterpret_cast<const s16x8*>(
                    &ekv[4 + w][16 * t + m][32 * kt + 8 * hq]);
                eb[t] = *reinterpret_cast<const s16x8*>(
                    &ekv[w][16 * t + m][32 * kt + 8 * hq]);
            }
#pragma unroll
            for (int tm = 0; tm < 2; ++tm)
#pragma unroll
                for (int tn = 0; tn < 2; ++tn)
                    cacc[tm][tn] = __builtin_amdgcn_mfma_f32_16x16x32_bf16(
                        va[tm], eb[tn], cacc[tm][tn], 0, 0, 0);
        }
        __syncthreads();  // S3: loop-end fence (keeps VGPR low; WAR safety)
    }

    float* pc = ws + PC_OFF + (size_t)((b * 4 + w) * NCH + j) * 1024;
#pragma unroll
    for (int tm = 0; tm < 2; ++tm)
#pragma unroll
        for (int tn = 0; tn < 2; ++tn)
#pragma unroll
            for (int r = 0; r < 4; ++r)
                pc[(16 * tm + 4 * hq + r) * 32 + 16 * tn + m] = cacc[tm][tn][r];

    if (w < 2) {
#pragma unroll
        for (int tm = 0; tm < 4; ++tm)
#pragma unroll
            for (int r = 0; r < 4; ++r) {
                float s = sacc[tm][r];
                s += __shfl_xor(s, 1);
                s += __shfl_xor(s, 2);
                s += __shfl_xor(s, 4);
                s += __shfl_xor(s, 8);
                if (m == 0) {
                    const int dg = 64 * w + 16 * tm + 4 * hq + r;
                    ws[PS_OFF + (size_t)((b * 4 + (dg >> 5)) * NCH + j) * 32 + (dg & 31)] = s;
                }
            }
    }
}

// ---------------------------------------------------------------------------
// k2a: merge partials -> normalized ctx. One block per (b,h).
// unroll-8 on the jj loops: 8 independent loads in flight (latency/8).
// ---------------------------------------------------------------------------
__global__ __launch_bounds__(256)
void k2a_ctx(float* __restrict__ ws) {
    const int bh = blockIdx.x;
    const int tid = threadIdx.x;
    __shared__ float stotS[32];
    if (tid < 32) {
        float s = 0.f;
#pragma unroll 8
        for (int jj = 0; jj < NCH; ++jj)
            s += ws[PS_OFF + (size_t)(bh * NCH + jj) * 32 + tid];
        stotS[tid] = s;
    }
    __syncthreads();
#pragma unroll
    for (int k = 0; k < 4; ++k) {
        const int idx = tid + 256 * k;  // e*32 + d
        float c = 0.f;
#pragma unroll 8
        for (int jj = 0; jj < NCH; ++jj)
            c += ws[PC_OFF + (size_t)(bh * NCH + jj) * 1024 + idx];
        ws[CTX_OFF + (size_t)bh * 1024 + idx] = c / stotS[idx & 31];
    }
}

// ---------------------------------------------------------------------------
// k2b: M[b] = W_out . BD(ctx) . W_q -> bf16.  grid (4 o-tiles, 32 batches).
// ---------------------------------------------------------------------------
__global__ __launch_bounds__(256)
void k2b_buildM(const float* __restrict__ wqkv, const float* __restrict__ wout,
                float* __restrict__ ws) {
    const int oq = blockIdx.x;
    const int b  = blockIdx.y;
    const int tid = threadIdx.x;

    __shared__ __attribute__((aligned(16))) float smA[8704];
    __shared__ float G[32][133];
    float* ctxs  = smA;          // [hd][33]
    float* wouts = smA + 4224;   // [o][133]
    unsigned int* wqs = (unsigned int*)smA;  // phase B: [hd][68] dwords

#pragma unroll
    for (int k = 0; k < 16; ++k) {
        const int fid = tid + 256 * k;          // h*1024 + e*32 + d
        const int h = fid >> 10, rem = fid & 1023;
        const int e = rem >> 5, d = rem & 31;
        ctxs[(h * 32 + d) * 33 + e] = ws[CTX_OFF + (size_t)b * 4096 + fid];
    }
#pragma unroll
    for (int k = 0; k < 16; ++k) {
        const int fid = tid + 256 * k;          // o*128 + c
        const int o = fid >> 7, c = fid & 127;
        wouts[o * 133 + c] = wout[(size_t)(oq * 32 + o) * CDIM + c];
    }
    __syncthreads();

    {
        const int o2 = tid & 31;
        const int g8 = tid >> 5;
#pragma unroll
        for (int i = 0; i < 16; ++i) {
            const int hd = g8 * 16 + i;
            const int h = hd >> 5;
            float acc = 0.f;
#pragma unroll
            for (int e = 0; e < 32; ++e)
                acc = fmaf(wouts[o2 * 133 + h * 32 + e], ctxs[hd * 33 + e], acc);
            G[o2][hd] = acc;
        }
    }
    __syncthreads();

    {
#pragma unroll
        for (int k = 0; k < 32; ++k) {
            const int fid = tid + 256 * k;      // hd*64 + cd
            const int hd = fid >> 6, cd = fid & 63;
            const float2 wv =
                *reinterpret_cast<const float2*>(wqkv + (size_t)hd * CDIM + 2 * cd);
            wqs[hd * 68 + cd] = pack2(wv.x, wv.y);
        }
    }
    __syncthreads();

    {
        const int o3 = tid >> 3;
        const int c0 = tid & 7;
        float Macc[16];
#pragma unroll
        for (int i = 0; i < 16; ++i) Macc[i] = 0.f;
        for (int hd = 0; hd < 128; ++hd) {
            const float gv = G[o3][hd];
            const uint4 w0 = *reinterpret_cast<const uint4*>(&wqs[hd * 68 + c0 * 8]);
            const uint4 w1 = *reinterpret_cast<const uint4*>(&wqs[hd * 68 + c0 * 8 + 4]);
            const unsigned int dw[8] = {w0.x, w0.y, w0.z, w0.w, w1.x, w1.y, w1.z, w1.w};
#pragma unroll
            for (int q = 0; q < 8; ++q) {
                const float lo = __builtin_bit_cast(float, dw[q] << 16);
                const float hi = __builtin_bit_cast(float, dw[q] & 0xffff0000u);
                Macc[2 * q]     = fmaf(gv, lo, Macc[2 * q]);
                Macc[2 * q + 1] = fmaf(gv, hi, Macc[2 * q + 1]);
            }
        }
        unsigned int* mpd = (unsigned int*)((unsigned short*)(ws + MBF_OFF) +
                                            (size_t)b * CDIM * CDIM) +
                            (oq * 32 + o3) * 64 + c0 * 8;
        uint4 s0, s1;
        s0.x = pack2(Macc[0], Macc[1]);   s0.y = pack2(Macc[2], Macc[3]);
        s0.z = pack2(Macc[4], Macc[5]);   s0.w = pack2(Macc[6], Macc[7]);
        s1.x = pack2(Macc[8], Macc[9]);   s1.y = pack2(Macc[10], Macc[11]);
        s1.z = pack2(Macc[12], Macc[13]); s1.w = pack2(Macc[14], Macc[15]);
        *reinterpret_cast<uint4*>(mpd) = s0;
        *reinterpret_cast<uint4*>(mpd + 4) = s1;
    }
}

// ---------------------------------------------------------------------------
// k3: out[b] = M_bf16[b] @ x_bf16[b] + b_out.  (R6/R9-verified: plain uint4
// reg-copy of pre-swizzled tiles, 2 syncthreads/iter.)
// ---------------------------------------------------------------------------
template <bool XBT>
__global__ __launch_bounds__(256)
void k3_final(const float* __restrict__ x, const float* __restrict__ bout,
              const float* __restrict__ ws, float* __restrict__ out) {
    __shared__ __attribute__((aligned(16))) unsigned int xsd[4160];

    const int j = blockIdx.x, b = blockIdx.y;
    const int tid = threadIdx.x, l = tid & 63, w = tid >> 6;
    const int m = l & 15, hq = l >> 4;

    const unsigned short* mbf =
        (const unsigned short*)(ws + MBF_OFF) + (size_t)b * CDIM * CDIM;
    s16x8 afr[2][4];
#pragma unroll
    for (int tm = 0; tm < 2; ++tm)
#pragma unroll
        for (int kt = 0; kt < 4; ++kt)
            afr[tm][kt] = *reinterpret_cast<const s16x8*>(
                mbf + (size_t)(32 * w + 16 * tm + m) * CDIM + 32 * kt + 8 * hq);
    float bias[2][4];
#pragma unroll
    for (int tm = 0; tm < 2; ++tm)
#pragma unroll
        for (int r = 0; r < 4; ++r)
            bias[tm][r] = bout[32 * w + 16 * tm + 4 * hq + r];

    const float* xc = x + (size_t)b * CDIM * NTOT + j * 256;
    float* oc = out + (size_t)b * CDIM * NTOT + j * 256;
    const unsigned int* tb = (const unsigned int*)(ws + XBT_OFF) +
                             ((size_t)b * 64 + j * 4) * 4096;

    for (int it = 0; it < 4; ++it) {
        if constexpr (XBT) {
            const unsigned int* src = tb + it * 4096;
#pragma unroll
            for (int rep = 0; rep < 4; ++rep) {
                const int dw = rep * 1024 + tid * 4;
                *reinterpret_cast<uint4*>(&xsd[dw]) =
                    *reinterpret_cast<const uint4*>(src + dw);
            }
        } else {
            stage_xT(xc + it * TN, xsd, tid);
        }
        __syncthreads();

        f32x4 acc[2][4] = {};
#pragma unroll
        for (int kt = 0; kt < 4; ++kt) {
#pragma unroll
            for (int tn = 0; tn < 4; ++tn) {
                const int nl = 16 * tn + m;
                s16x8 bfr;
                if constexpr (XBT) {
                    const int idx = nl * 64 + ((16 * kt + 4 * hq) ^ ((nl & 7) << 2));
                    bfr = __builtin_bit_cast(
                        s16x8, *reinterpret_cast<const int4*>(&xsd[idx]));
                } else {
                    bfr = ld_frag_lds(xsd, nl * 65 + 16 * kt + 4 * hq);
                }
#pragma unroll
                for (int tm = 0; tm < 2; ++tm)
                    acc[tm][tn] = __builtin_amdgcn_mfma_f32_16x16x32_bf16(
                        afr[tm][kt], bfr, acc[tm][tn], 0, 0, 0);
            }
        }
#pragma unroll
        for (int tm = 0; tm < 2; ++tm)
#pragma unroll
            for (int tn = 0; tn < 4; ++tn)
#pragma unroll
                for (int r = 0; r < 4; ++r)
                    oc[(size_t)(32 * w + 16 * tm + 4 * hq + r) * NTOT +
                       it * TN + 16 * tn + m] = acc[tm][tn][r] + bias[tm][r];
        __syncthreads();
    }
}

extern "C" void kernel_launch(void* const* d_in, const int* in_sizes, int n_in,
                              void* d_out, int out_size, void* d_ws, size_t ws_size,
                              hipStream_t stream) {
    const float* x    = (const float*)d_in[0];
    const float* wqkv = (const float*)d_in[1];
    const float* wout = (const float*)d_in[2];
    const float* bout = (const float*)d_in[3];
    float* out = (float*)d_out;
    float* ws  = (float*)d_ws;

    const bool xbt = ws_size >= NEED_BYTES;

    if (xbt)
        k1_ctx<true><<<dim3(NCH, BATCH), 256, 0, stream>>>(x, wqkv, ws);
    else
        k1_ctx<false><<<dim3(NCH, BATCH), 256, 0, stream>>>(x, wqkv, ws);

    k2a_ctx<<<BATCH * 4, 256, 0, stream>>>(ws);
    k2b_buildM<<<dim3(4, BATCH), 256, 0, stream>>>(wqkv, wout, ws);

    if (xbt)
        k3_final<true><<<dim3(NCH3, BATCH), 256, 0, stream>>>(x, bout, ws, out);
    else
        k3_final<false><<<dim3(NCH3, BATCH), 256, 0, stream>>>(x, bout, ws, out);
}

// Round 15
// 85.782 us; speedup vs baseline: 1.3672x; 1.0250x over previous
//
#include <hip/hip_runtime.h>
#include <hip/hip_bf16.h>
#include <math.h>

#define BATCH 32
#define CDIM  128
#define NTOT  4096
#define NCH   16           // k1 chunks per batch
#define NCH2  (NCH * 2)    // ctx partial slots (n-half split across wave pairs)
#define CHN   256          // n per k1 block
#define TN    64           // n per subtile
#define NCH3  16           // k3 chunks per batch

typedef __attribute__((ext_vector_type(4))) float f32x4;
typedef __attribute__((ext_vector_type(8))) short s16x8;

// ---- ws layout (float offsets) ----
#define PC_OFF  0
#define PC_SIZE (BATCH * 4 * NCH2 * 32 * 32)  // 4,194,304 f
#define PS_OFF  (PC_OFF + PC_SIZE)
#define PS_SIZE (BATCH * 4 * NCH * 32)        // 65,536 f
#define MBF_OFF (PS_OFF + PS_SIZE)
#define MBF_SIZE (BATCH * CDIM * CDIM / 2)    // 262,144 f
#define CTX_OFF (MBF_OFF + MBF_SIZE)
#define CTX_SIZE (BATCH * 4 * 1024)           // 131,072 f
#define XBT_OFF (CTX_OFF + CTX_SIZE)
#define XBT_SIZE (BATCH * CDIM * NTOT / 2)    // 8,388,608 f
#define NEED_BYTES ((size_t)(XBT_OFF + XBT_SIZE) * 4)   // ~52.2 MB

static __device__ __forceinline__ unsigned short f2bf(float f) {
    return __builtin_bit_cast(unsigned short, __float2bfloat16(f));
}
static __device__ __forceinline__ unsigned int pack2(float a, float b) {
    return (unsigned int)f2bf(a) | ((unsigned int)f2bf(b) << 16);
}
static __device__ __forceinline__ s16x8 ld_frag_lds(const unsigned int* p, int d0) {
    int4 t;
    t.x = (int)p[d0]; t.y = (int)p[d0 + 1];
    t.z = (int)p[d0 + 2]; t.w = (int)p[d0 + 3];
    return __builtin_bit_cast(s16x8, t);
}

// 256-thread staging (k3 fallback path only)
static __device__ __forceinline__ void stage_xT(const float* __restrict__ xc,
                                                unsigned int* __restrict__ xsd,
                                                int tid) {
    const int m  = tid & 15;
    const int cg = tid >> 4;
#pragma unroll
    for (int p = 0; p < 4; ++p) {
        const int c = 2 * cg + 32 * p;
        const f32x4 a0 = *reinterpret_cast<const f32x4*>(xc + (size_t)c * NTOT + 4 * m);
        const f32x4 a1 = *reinterpret_cast<const f32x4*>(xc + (size_t)(c + 1) * NTOT + 4 * m);
#pragma unroll
        for (int jj = 0; jj < 4; ++jj)
            xsd[(4 * m + jj) * 65 + (c >> 1)] = pack2(a0[jj], a1[jj]);
    }
}

// ---------------------------------------------------------------------------
// k1: 512 threads / 8 thin waves. Each wave owns 32 KV rows (halved fragment
// footprint: afr[2][4]+acc[2][4] = 64 VGPR vs 128) -> 16 waves/CU at the same
// 53.5 KB LDS. ctx-MFMA: wave = (head w>>1, n-half w&1); partials to NCH2
// slots. 3-barrier loop (R14-verified VGPR fence). NCH=16 (R6-best grid).
// ---------------------------------------------------------------------------
template <bool XBT>
__global__ __launch_bounds__(512)
void k1_ctx(const float* __restrict__ x, const float* __restrict__ wqkv,
            float* __restrict__ ws) {
    __shared__ __attribute__((aligned(16))) unsigned short xsT[64 * 130];   // 16.6 KB
    __shared__ __attribute__((aligned(16))) unsigned short ekv[8][32][72];  // 36.9 KB

    const int j = blockIdx.x, b = blockIdx.y;
    const int tid = threadIdx.x;
    const int l = tid & 63;
    const int w = tid >> 6;          // 0..7
    const int m = l & 15, hq = l >> 4;
    const int m16 = tid & 15, cg = tid >> 4;   // stage mapping (cg 0..31)

    // A fragments: W_kv rows 128 + 32w + 16tm + m (w 0-3 = K, 4-7 = V)
    s16x8 afr[2][4];
#pragma unroll
    for (int tm = 0; tm < 2; ++tm)
#pragma unroll
        for (int kt = 0; kt < 4; ++kt) {
            const float* wr = wqkv +
                (size_t)(CDIM + 32 * w + 16 * tm + m) * CDIM + 32 * kt + 8 * hq;
            const f32x4 u0 = *reinterpret_cast<const f32x4*>(wr);
            const f32x4 u1 = *reinterpret_cast<const f32x4*>(wr + 4);
            int4 t4;
            t4.x = (int)pack2(u0[0], u0[1]); t4.y = (int)pack2(u0[2], u0[3]);
            t4.z = (int)pack2(u1[0], u1[1]); t4.w = (int)pack2(u1[2], u1[3]);
            afr[tm][kt] = __builtin_bit_cast(s16x8, t4);
        }

    f32x4 cacc[2][2] = {};
    float sacc[2][4] = {};
    const int h  = w >> 1;           // ctx head
    const int ks = w & 1;            // ctx n-half (kt slice)
    const float* xc = x + (size_t)b * CDIM * NTOT + j * CHN;
    unsigned int* xsd = (unsigned int*)xsT;

    for (int it = 0; it < CHN / TN; ++it) {
        // ---- stage: 512 threads, each 2 row-pairs ----
#pragma unroll
        for (int p = 0; p < 2; ++p) {
            const int c = 2 * cg + 64 * p;
            const f32x4 a0 = *reinterpret_cast<const f32x4*>(
                xc + (size_t)(it * TN) + (size_t)c * NTOT + 4 * m16);
            const f32x4 a1 = *reinterpret_cast<const f32x4*>(
                xc + (size_t)(it * TN) + (size_t)(c + 1) * NTOT + 4 * m16);
#pragma unroll
            for (int jj = 0; jj < 4; ++jj)
                xsd[(4 * m16 + jj) * 65 + (c >> 1)] = pack2(a0[jj], a1[jj]);
        }
        __syncthreads();  // S1: xsT ready

        // ---- KV GEMM: 32 rows per wave ----
        f32x4 acc[2][4] = {};
#pragma unroll
        for (int kt = 0; kt < 4; ++kt) {
#pragma unroll
            for (int tn = 0; tn < 4; ++tn) {
                const s16x8 bfr = ld_frag_lds(xsd, (16 * tn + m) * 65 + 16 * kt + 4 * hq);
#pragma unroll
                for (int tm = 0; tm < 2; ++tm)
                    acc[tm][tn] = __builtin_amdgcn_mfma_f32_16x16x32_bf16(
                        afr[tm][kt], bfr, acc[tm][tn], 0, 0, 0);
            }
        }

        // ---- persist swizzled bf16 tile for k3 (tile = b*64 + j*4 + it) ----
        if constexpr (XBT) {
            unsigned int* tb = (unsigned int*)(ws + XBT_OFF) +
                               ((size_t)b * 64 + j * 4 + it) * 4096;
            const int n = tid >> 3, qt = tid & 7;
#pragma unroll
            for (int p = 0; p < 2; ++p) {
                const int cdl = 32 * p + 4 * qt;
                const int src = n * 65 + (cdl ^ ((n & 7) << 2));
                uint4 v;
                v.x = xsd[src]; v.y = xsd[src + 1];
                v.z = xsd[src + 2]; v.w = xsd[src + 3];
                *reinterpret_cast<uint4*>(tb + (size_t)n * 64 + cdl) = v;
            }
        }

        // ---- exp(K) -> ekv[0..3] (waves 0-3), V -> ekv[4..7] (waves 4-7) ----
        if (w < 4) {
#pragma unroll
            for (int tm = 0; tm < 2; ++tm)
#pragma unroll
                for (int tn = 0; tn < 4; ++tn)
#pragma unroll
                    for (int r = 0; r < 4; ++r) {
                        const int dg = 32 * w + 16 * tm + 4 * hq + r;
                        const float e = __expf(acc[tm][tn][r]);
                        sacc[tm][r] += e;
                        ekv[dg >> 5][dg & 31][16 * tn + m] = f2bf(e);
                    }
        } else {
#pragma unroll
            for (int tm = 0; tm < 2; ++tm)
#pragma unroll
                for (int tn = 0; tn < 4; ++tn)
#pragma unroll
                    for (int r = 0; r < 4; ++r) {
                        const int eg = 32 * (w - 4) + 16 * tm + 4 * hq + r;
                        ekv[4 + (eg >> 5)][eg & 31][16 * tn + m] = f2bf(acc[tm][tn][r]);
                    }
        }
        __syncthreads();  // S2: ekv ready

        // ---- ctx MFMA: wave (h, ks); contracts its 32-col n-half ----
        {
            s16x8 va[2], eb[2];
#pragma unroll
            for (int t = 0; t < 2; ++t) {
                va[t] = *reinterpret_cast<const s16x8*>(
                    &ekv[4 + h][16 * t + m][32 * ks + 8 * hq]);
                eb[t] = *reinterpret_cast<const s16x8*>(
                    &ekv[h][16 * t + m][32 * ks + 8 * hq]);
            }
#pragma unroll
            for (int tm = 0; tm < 2; ++tm)
#pragma unroll
                for (int tn = 0; tn < 2; ++tn)
                    cacc[tm][tn] = __builtin_amdgcn_mfma_f32_16x16x32_bf16(
                        va[tm], eb[tn], cacc[tm][tn], 0, 0, 0);
        }
        __syncthreads();  // S3: loop-end fence (VGPR hoist-block + WAR safety)
    }

    // ---- ctx partials: slot j2 = j*2 + ks ----
    float* pc = ws + PC_OFF + (size_t)((b * 4 + h) * NCH2 + (j * 2 + ks)) * 1024;
#pragma unroll
    for (int tm = 0; tm < 2; ++tm)
#pragma unroll
        for (int tn = 0; tn < 2; ++tn)
#pragma unroll
            for (int r = 0; r < 4; ++r)
                pc[(16 * tm + 4 * hq + r) * 32 + 16 * tn + m] = cacc[tm][tn][r];

    // ---- s partials (full column coverage per wave): slot j ----
    if (w < 4) {
#pragma unroll
        for (int tm = 0; tm < 2; ++tm)
#pragma unroll
            for (int r = 0; r < 4; ++r) {
                float s = sacc[tm][r];
                s += __shfl_xor(s, 1);
                s += __shfl_xor(s, 2);
                s += __shfl_xor(s, 4);
                s += __shfl_xor(s, 8);
                if (m == 0) {
                    const int dg = 32 * w + 16 * tm + 4 * hq + r;
                    ws[PS_OFF + (size_t)((b * 4 + (dg >> 5)) * NCH + j) * 32 + (dg & 31)] = s;
                }
            }
    }
}

// ---------------------------------------------------------------------------
// k2a: merge partials -> normalized ctx. One block per (b,h); unroll-8.
// ---------------------------------------------------------------------------
__global__ __launch_bounds__(256)
void k2a_ctx(float* __restrict__ ws) {
    const int bh = blockIdx.x;
    const int tid = threadIdx.x;
    __shared__ float stotS[32];
    if (tid < 32) {
        float s = 0.f;
#pragma unroll 8
        for (int jj = 0; jj < NCH; ++jj)
            s += ws[PS_OFF + (size_t)(bh * NCH + jj) * 32 + tid];
        stotS[tid] = s;
    }
    __syncthreads();
#pragma unroll
    for (int k = 0; k < 4; ++k) {
        const int idx = tid + 256 * k;  // e*32 + d
        float c = 0.f;
#pragma unroll 8
        for (int jj = 0; jj < NCH2; ++jj)
            c += ws[PC_OFF + (size_t)(bh * NCH2 + jj) * 1024 + idx];
        ws[CTX_OFF + (size_t)bh * 1024 + idx] = c / stotS[idx & 31];
    }
}

// ---------------------------------------------------------------------------
// k2b: M[b] = W_out . BD(ctx) . W_q -> bf16.  grid (4 o-tiles, 32 batches).
// ---------------------------------------------------------------------------
__global__ __launch_bounds__(256)
void k2b_buildM(const float* __restrict__ wqkv, const float* __restrict__ wout,
                float* __restrict__ ws) {
    const int oq = blockIdx.x;
    const int b  = blockIdx.y;
    const int tid = threadIdx.x;

    __shared__ __attribute__((aligned(16))) float smA[8704];
    __shared__ float G[32][133];
    float* ctxs  = smA;          // [hd][33]
    float* wouts = smA + 4224;   // [o][133]
    unsigned int* wqs = (unsigned int*)smA;  // phase B: [hd][68] dwords

#pragma unroll
    for (int k = 0; k < 16; ++k) {
        const int fid = tid + 256 * k;          // h*1024 + e*32 + d
        const int h = fid >> 10, rem = fid & 1023;
        const int e = rem >> 5, d = rem & 31;
        ctxs[(h * 32 + d) * 33 + e] = ws[CTX_OFF + (size_t)b * 4096 + fid];
    }
#pragma unroll
    for (int k = 0; k < 16; ++k) {
        const int fid = tid + 256 * k;          // o*128 + c
        const int o = fid >> 7, c = fid & 127;
        wouts[o * 133 + c] = wout[(size_t)(oq * 32 + o) * CDIM + c];
    }
    __syncthreads();

    {
        const int o2 = tid & 31;
        const int g8 = tid >> 5;
#pragma unroll
        for (int i = 0; i < 16; ++i) {
            const int hd = g8 * 16 + i;
            const int h = hd >> 5;
            float acc = 0.f;
#pragma unroll
            for (int e = 0; e < 32; ++e)
                acc = fmaf(wouts[o2 * 133 + h * 32 + e], ctxs[hd * 33 + e], acc);
            G[o2][hd] = acc;
        }
    }
    __syncthreads();

    {
#pragma unroll
        for (int k = 0; k < 32; ++k) {
            const int fid = tid + 256 * k;      // hd*64 + cd
            const int hd = fid >> 6, cd = fid & 63;
            const float2 wv =
                *reinterpret_cast<const float2*>(wqkv + (size_t)hd * CDIM + 2 * cd);
            wqs[hd * 68 + cd] = pack2(wv.x, wv.y);
        }
    }
    __syncthreads();

    {
        const int o3 = tid >> 3;
        const int c0 = tid & 7;
        float Macc[16];
#pragma unroll
        for (int i = 0; i < 16; ++i) Macc[i] = 0.f;
        for (int hd = 0; hd < 128; ++hd) {
            const float gv = G[o3][hd];
            const uint4 w0 = *reinterpret_cast<const uint4*>(&wqs[hd * 68 + c0 * 8]);
            const uint4 w1 = *reinterpret_cast<const uint4*>(&wqs[hd * 68 + c0 * 8 + 4]);
            const unsigned int dw[8] = {w0.x, w0.y, w0.z, w0.w, w1.x, w1.y, w1.z, w1.w};
#pragma unroll
            for (int q = 0; q < 8; ++q) {
                const float lo = __builtin_bit_cast(float, dw[q] << 16);
                const float hi = __builtin_bit_cast(float, dw[q] & 0xffff0000u);
                Macc[2 * q]     = fmaf(gv, lo, Macc[2 * q]);
                Macc[2 * q + 1] = fmaf(gv, hi, Macc[2 * q + 1]);
            }
        }
        unsigned int* mpd = (unsigned int*)((unsigned short*)(ws + MBF_OFF) +
                                            (size_t)b * CDIM * CDIM) +
                            (oq * 32 + o3) * 64 + c0 * 8;
        uint4 s0, s1;
        s0.x = pack2(Macc[0], Macc[1]);   s0.y = pack2(Macc[2], Macc[3]);
        s0.z = pack2(Macc[4], Macc[5]);   s0.w = pack2(Macc[6], Macc[7]);
        s1.x = pack2(Macc[8], Macc[9]);   s1.y = pack2(Macc[10], Macc[11]);
        s1.z = pack2(Macc[12], Macc[13]); s1.w = pack2(Macc[14], Macc[15]);
        *reinterpret_cast<uint4*>(mpd) = s0;
        *reinterpret_cast<uint4*>(mpd + 4) = s1;
    }
}

// ---------------------------------------------------------------------------
// k3: out[b] = M_bf16[b] @ x_bf16[b] + b_out.  (R6/R9-verified staging.)
// ---------------------------------------------------------------------------
template <bool XBT>
__global__ __launch_bounds__(256)
void k3_final(const float* __restrict__ x, const float* __restrict__ bout,
              const float* __restrict__ ws, float* __restrict__ out) {
    __shared__ __attribute__((aligned(16))) unsigned int xsd[4160];

    const int j = blockIdx.x, b = blockIdx.y;
    const int tid = threadIdx.x, l = tid & 63, w = tid >> 6;
    const int m = l & 15, hq = l >> 4;

    const unsigned short* mbf =
        (const unsigned short*)(ws + MBF_OFF) + (size_t)b * CDIM * CDIM;
    s16x8 afr[2][4];
#pragma unroll
    for (int tm = 0; tm < 2; ++tm)
#pragma unroll
        for (int kt = 0; kt < 4; ++kt)
            afr[tm][kt] = *reinterpret_cast<const s16x8*>(
                mbf + (size_t)(32 * w + 16 * tm + m) * CDIM + 32 * kt + 8 * hq);
    float bias[2][4];
#pragma unroll
    for (int tm = 0; tm < 2; ++tm)
#pragma unroll
        for (int r = 0; r < 4; ++r)
            bias[tm][r] = bout[32 * w + 16 * tm + 4 * hq + r];

    const float* xc = x + (size_t)b * CDIM * NTOT + j * 256;
    float* oc = out + (size_t)b * CDIM * NTOT + j * 256;
    const unsigned int* tb = (const unsigned int*)(ws + XBT_OFF) +
                             ((size_t)b * 64 + j * 4) * 4096;

    for (int it = 0; it < 4; ++it) {
        if constexpr (XBT) {
            const unsigned int* src = tb + it * 4096;
#pragma unroll
            for (int rep = 0; rep < 4; ++rep) {
                const int dw = rep * 1024 + tid * 4;
                *reinterpret_cast<uint4*>(&xsd[dw]) =
                    *reinterpret_cast<const uint4*>(src + dw);
            }
        } else {
            stage_xT(xc + it * TN, xsd, tid);
        }
        __syncthreads();

        f32x4 acc[2][4] = {};
#pragma unroll
        for (int kt = 0; kt < 4; ++kt) {
#pragma unroll
            for (int tn = 0; tn < 4; ++tn) {
                const int nl = 16 * tn + m;
                s16x8 bfr;
                if constexpr (XBT) {
                    const int idx = nl * 64 + ((16 * kt + 4 * hq) ^ ((nl & 7) << 2));
                    bfr = __builtin_bit_cast(
                        s16x8, *reinterpret_cast<const int4*>(&xsd[idx]));
                } else {
                    bfr = ld_frag_lds(xsd, nl * 65 + 16 * kt + 4 * hq);
                }
#pragma unroll
                for (int tm = 0; tm < 2; ++tm)
                    acc[tm][tn] = __builtin_amdgcn_mfma_f32_16x16x32_bf16(
                        afr[tm][kt], bfr, acc[tm][tn], 0, 0, 0);
            }
        }
#pragma unroll
        for (int tm = 0; tm < 2; ++tm)
#pragma unroll
            for (int tn = 0; tn < 4; ++tn)
#pragma unroll
                for (int r = 0; r < 4; ++r)
                    oc[(size_t)(32 * w + 16 * tm + 4 * hq + r) * NTOT +
                       it * TN + 16 * tn + m] = acc[tm][tn][r] + bias[tm][r];
        __syncthreads();
    }
}

extern "C" void kernel_launch(void* const* d_in, const int* in_sizes, int n_in,
                              void* d_out, int out_size, void* d_ws, size_t ws_size,
                              hipStream_t stream) {
    const float* x    = (const float*)d_in[0];
    const float* wqkv = (const float*)d_in[1];
    const float* wout = (const float*)d_in[2];
    const float* bout = (const float*)d_in[3];
    float* out = (float*)d_out;
    float* ws  = (float*)d_ws;

    const bool xbt = ws_size >= NEED_BYTES;

    if (xbt)
        k1_ctx<true><<<dim3(NCH, BATCH), 512, 0, stream>>>(x, wqkv, ws);
    else
        k1_ctx<false><<<dim3(NCH, BATCH), 512, 0, stream>>>(x, wqkv, ws);

    k2a_ctx<<<BATCH * 4, 256, 0, stream>>>(ws);
    k2b_buildM<<<dim3(4, BATCH), 256, 0, stream>>>(wqkv, wout, ws);

    if (xbt)
        k3_final<true><<<dim3(NCH3, BATCH), 256, 0, stream>>>(x, bout, ws, out);
    else
        k3_final<false><<<dim3(NCH3, BATCH), 256, 0, stream>>>(x, bout, ws, out);
}